// Round 4
// baseline (82.275 us; speedup 1.0000x reference)
//
#include <hip/hip_runtime.h>

#define KS 10
#define NT 256
#define CHUNK 2048   // level-0 samples per block (excl. halo)

// Level geometry (CHUNK=2048):
//  x  ext: [x0-60,  x0+2108)  count 2168   (pad 60 each side)
//  a1 ext: [o1-28,  o1+1052)  count 1080   pad 28, own 1024
//  a2 ext: [o2-12,  o2+524 )  count 536    pad 12, own 512
//  a3 ext: [o3-4,   o3+260 )  count 264    pad 4,  own 256
//  a4     : own only          count 128
// Slot identity: output slot t reads input slots [2t, 2t+10).
// Pair p -> outputs {2p, 2p+1} -> input slots [4p, 4p+12): 3 aligned float4,
// 16B lane stride => conflict-free ds_read_b128.

struct OutPtrs { float* a[4]; float* d[4]; };

template<int EXT, bool LAST>
__device__ __forceinline__ void level_pass(const float* __restrict__ sIn,
                                           float* __restrict__ sOut,
                                           const float* h, const float* g,
                                           float2* dreg, float2* areg, int tid)
{
    constexpr int NP = EXT / 2;
    constexpr int ITERS = (NP + NT - 1) / NT;
#pragma unroll
    for (int i = 0; i < ITERS; ++i) {
        const int p = tid + i * NT;
        if (p < NP) {
            const float4* bp = reinterpret_cast<const float4*>(sIn + 4 * p);
            const float4 v0 = bp[0], v1 = bp[1], v2 = bp[2];
            const float xin[12] = {v0.x, v0.y, v0.z, v0.w,
                                   v1.x, v1.y, v1.z, v1.w,
                                   v2.x, v2.y, v2.z, v2.w};
            float a0 = 0.f, a1 = 0.f, d0 = 0.f, d1 = 0.f;
#pragma unroll
            for (int k = 0; k < KS; ++k) {
                a0 = fmaf(xin[k],     h[k], a0);
                d0 = fmaf(xin[k],     g[k], d0);
                a1 = fmaf(xin[k + 2], h[k], a1);
                d1 = fmaf(xin[k + 2], g[k], d1);
            }
            if (LAST) areg[i] = make_float2(a0, a1);
            else      reinterpret_cast<float2*>(sOut)[p] = make_float2(a0, a1);
            dreg[i] = make_float2(d0, d1);
        }
    }
}

// patch antireflect halo slots of an LDS level buffer (edge blocks only)
__device__ __forceinline__ void patch(float* sa, int P, int N, bool left, bool right, int tid)
{
    if (left && tid < P)
        sa[tid] = 2.0f * sa[P] - sa[2 * P - tid];
    if (right && tid < P) {
        const int E = P + N - 1;
        const int t = P + N + tid;
        sa[t] = 2.0f * sa[E] - sa[2 * E - t];
    }
}

template<int ITERS, int PADO, int OWN>
__device__ __forceinline__ void store_d(float* __restrict__ grow, const float2* dreg, int tid)
{
#pragma unroll
    for (int i = 0; i < ITERS; ++i) {
        const int t0 = 2 * (tid + i * NT);
        if (t0 >= PADO && t0 < PADO + OWN)
            *reinterpret_cast<float2*>(grow + (t0 - PADO)) = dreg[i];
    }
}

__global__ __launch_bounds__(NT) void dwt_fused_kernel(
    const float* __restrict__ x, const float* __restrict__ hptr, OutPtrs op, int L0)
{
    const int row = blockIdx.y;
    const int c   = blockIdx.x;
    const int nc  = gridDim.x;
    const int tid = threadIdx.x;
    const bool left  = (c == 0);
    const bool right = (c == nc - 1);
    const bool edge  = left || right;

    const int L1 = L0 >> 1, L2 = L0 >> 2, L3 = L0 >> 3, L4 = L0 >> 4;
    const int o1 = c * (CHUNK >> 1), o2 = c * (CHUNK >> 2),
              o3 = c * (CHUNK >> 3), o4 = c * (CHUNK >> 4);
    const int s0 = c * CHUNK - 60;

    __shared__ __align__(16) float sx [2168];
    __shared__ __align__(16) float sa1[1080];
    __shared__ __align__(16) float sa2[536];
    __shared__ __align__(16) float sa3[264];

    float h[KS], g[KS];
#pragma unroll
    for (int k = 0; k < KS; ++k) h[k] = hptr[k];
#pragma unroll
    for (int k = 0; k < KS; ++k) g[k] = ((k & 1) ? -1.0f : 1.0f) * h[KS - 1 - k];

    // ---- stage x chunk (+halo) into LDS, fully vectorized for ALL blocks ----
    const float* xr = x + (size_t)row * (size_t)L0;
    {
        const int tlo = left ? 60 : 0;          // valid slot range [tlo, thi)
        const int thi = right ? 2108 : 2168;    // slot t holds x[s0+t]
        const int nf4 = (thi - tlo) >> 2;       // both bounds 16B-aligned
        const float4* src = reinterpret_cast<const float4*>(xr + s0 + tlo);
        float4* dst = reinterpret_cast<float4*>(sx + tlo);
        for (int j = tid; j < nf4; j += NT) dst[j] = src[j];
    }
    __syncthreads();
    if (edge) {
        // x-halo antireflect patch
        if (left && tid < 60)
            sx[tid] = 2.0f * sx[60] - sx[120 - tid];
        if (right && tid < 60) {
            const int t = 2108 + tid;           // x[L0-1] is slot 2107
            sx[t] = 2.0f * sx[2107] - sx[4214 - t];
        }
        __syncthreads();
    }

    // ---- cascade, all global writes deferred to the end ----
    float2 d1[3], d2[2], d3[1], d4[1], a4[1];

    level_pass<1080, false>(sx,  sa1, h, g, d1, nullptr, tid);
    __syncthreads();
    if (edge) { patch(sa1, 28, 1024, left, right, tid); __syncthreads(); }

    level_pass<536, false>(sa1, sa2, h, g, d2, nullptr, tid);
    __syncthreads();
    if (edge) { patch(sa2, 12, 512, left, right, tid); __syncthreads(); }

    level_pass<264, false>(sa2, sa3, h, g, d3, nullptr, tid);
    __syncthreads();
    if (edge) { patch(sa3, 4, 256, left, right, tid); __syncthreads(); }

    level_pass<128, true>(sa3, nullptr, h, g, d4, a4, tid);

    // ---- epilogue: write everything (no barriers after this point) ----
    const size_t r1 = (size_t)row * L1, r2 = (size_t)row * L2,
                 r3 = (size_t)row * L3, r4 = (size_t)row * L4;

    // a1..a3 from LDS own ranges as float4 (halo offsets 28/12/4 are 16B-aligned)
    reinterpret_cast<float4*>(op.a[0] + r1 + o1)[tid] =
        reinterpret_cast<const float4*>(sa1 + 28)[tid];                 // 1024
    if (tid < 128)
        reinterpret_cast<float4*>(op.a[1] + r2 + o2)[tid] =
            reinterpret_cast<const float4*>(sa2 + 12)[tid];             // 512
    if (tid < 64) {
        reinterpret_cast<float4*>(op.a[2] + r3 + o3)[tid] =
            reinterpret_cast<const float4*>(sa3 + 4)[tid];              // 256
        reinterpret_cast<float2*>(op.a[3] + r4 + o4)[tid] = a4[0];      // 128
        reinterpret_cast<float2*>(op.d[3] + r4 + o4)[tid] = d4[0];      // 128
    }

    store_d<3, 28, 1024>(op.d[0] + r1 + o1, d1, tid);
    store_d<2, 12, 512 >(op.d[1] + r2 + o2, d2, tid);
    store_d<1, 4,  256 >(op.d[2] + r3 + o3, d3, tid);
}

extern "C" void kernel_launch(void* const* d_in, const int* in_sizes, int n_in,
                              void* d_out, int out_size, void* d_ws, size_t ws_size,
                              hipStream_t stream) {
    (void)n_in; (void)d_ws; (void)ws_size; (void)out_size;

    const float* signal = (const float*)d_in[0];
    const float* h      = (const float*)d_in[1];
    float* out = (float*)d_out;

    const int L0 = 65536;
    const int R  = in_sizes[0] / L0;   // 512 rows
    const int LEVELS = 4;

    size_t s_off[4], d_off[4];
    {
        size_t off = 0;
        int L = L0;
        for (int l = 0; l < LEVELS; ++l) { s_off[l] = off; off += (size_t)R * (size_t)(L >> 1); L >>= 1; }
        L = L0;
        for (int l = 0; l < LEVELS; ++l) { d_off[l] = off; off += (size_t)R * (size_t)(L >> 1); L >>= 1; }
    }

    OutPtrs op;
    for (int l = 0; l < LEVELS; ++l) { op.a[l] = out + s_off[l]; op.d[l] = out + d_off[l]; }

    dim3 grid(L0 / CHUNK, R);   // 32 x 512 = 16384 blocks
    dim3 block(NT);
    dwt_fused_kernel<<<grid, block, 0, stream>>>(signal, h, op, L0);
}

// Round 5
// 79.509 us; speedup vs baseline: 1.0348x; 1.0348x over previous
//
#include <hip/hip_runtime.h>

#define KS 10
#define NT 256
#define W  512   // level-0 samples per WAVE (each wave fully independent)

// Per-wave LDS arena (floats):
//  sx  [632]  : x slots,  virtual [c*W-60, c*W+572)
//  sa1 [312]  : a1 slots, pad 28 | own 256 | pad 28
//  sa2 [152]  : a2 slots, pad 12 | own 128 | pad 12
//  sa3 [72]   : a3 slots, pad 4  | own 64  | pad 4
//  (a4/d4: 32 own, registers only)
// Slot identity: output slot t reads input slots [2t, 2t+10).
#define ARENA 1168

#define FENCE() asm volatile("s_waitcnt lgkmcnt(0)" ::: "memory")

struct OutPtrs { float* a[4]; float* d[4]; };

// one level: compute EXT extended outputs, write a to LDS, store own a/d to global
template<int EXT, int PADO, int OWN, bool TO_LDS>
__device__ __forceinline__ void wave_level(const float* __restrict__ sIn,
                                           float* __restrict__ sOut,
                                           const float* h,
                                           float* __restrict__ aRow,
                                           float* __restrict__ dRow,
                                           int obase, int lane)
{
    constexpr int ITERS = (EXT + 63) / 64;
#pragma unroll
    for (int i = 0; i < ITERS; ++i) {
        const int t = lane + 64 * i;
        if ((EXT % 64 == 0) || (t < EXT)) {
            float aa = 0.0f, dd = 0.0f;
#pragma unroll
            for (int k = 0; k < KS; ++k) {
                const float xv = sIn[2 * t + k];           // 8B lane stride: 2-way = free
                aa = fmaf(xv, h[k], aa);
                // g[k] = (-1)^k * h[9-k]; sign folds into fma input modifier
                dd = fmaf(xv, (k & 1) ? -h[KS - 1 - k] : h[KS - 1 - k], dd);
            }
            if (TO_LDS) sOut[t] = aa;
            const int rel = t - PADO;
            if (rel >= 0 && rel < OWN) {                   // store own range immediately
                aRow[obase + rel] = aa;                    // never drained: no barriers exist
                dRow[obase + rel] = dd;
            }
        }
    }
}

// antireflect halo patches (single masked wave op each)
__device__ __forceinline__ void patchL(float* s, int P, int lane) {
    if (lane < P) s[lane] = 2.0f * s[P] - s[2 * P - lane];
}
__device__ __forceinline__ void patchR(float* s, int P, int E, int lane) {
    if (lane < P) { const int t = E + 1 + lane; s[t] = 2.0f * s[E] - s[2 * E - t]; }
}

__global__ __launch_bounds__(NT) void dwt_wave_kernel(
    const float* __restrict__ x, const float* __restrict__ hptr, OutPtrs op, int L0)
{
    const int tid  = threadIdx.x;
    const int lane = tid & 63;
    const int wv   = tid >> 6;
    const int row  = blockIdx.y;
    const int nc   = L0 / W;                    // 128 chunks per row
    const int c    = blockIdx.x * (NT / 64) + wv;
    const bool left  = (c == 0);
    const bool right = (c == nc - 1);

    __shared__ __align__(16) float arena[(NT / 64) * ARENA];
    float* sw  = arena + wv * ARENA;
    float* sx  = sw;            // 632
    float* sa1 = sx  + 632;     // 312
    float* sa2 = sa1 + 312;     // 152
    float* sa3 = sa2 + 152;     // 72

    float h[KS];
#pragma unroll
    for (int k = 0; k < KS; ++k) h[k] = hptr[k];

    const int L1 = L0 >> 1, L2 = L0 >> 2, L3 = L0 >> 3, L4 = L0 >> 4;
    float* a0row = op.a[0] + (size_t)row * L1;  float* d0row = op.d[0] + (size_t)row * L1;
    float* a1row = op.a[1] + (size_t)row * L2;  float* d1row = op.d[1] + (size_t)row * L2;
    float* a2row = op.a[2] + (size_t)row * L3;  float* d2row = op.d[2] + (size_t)row * L3;
    float* a3row = op.a[3] + (size_t)row * L4;  float* d3row = op.d[3] + (size_t)row * L4;

    // ---- stage this wave's x chunk (+60 halo each side), vectorized ----
    const float* xr = x + (size_t)row * (size_t)L0;
    const int s0 = c * W - 60;                  // 16B-aligned element offset
    {
        const int tlo = left ? 60 : 0;          // valid slot range [tlo, thi)
        const int thi = right ? (W + 60) : (W + 120);
        const int nf4 = (thi - tlo) >> 2;
        const float4* src = reinterpret_cast<const float4*>(xr + s0 + tlo);
        float4* dst = reinterpret_cast<float4*>(sx + tlo);
        for (int j = lane; j < nf4; j += 64) dst[j] = src[j];
    }
    FENCE();
    if (left)  { patchL(sx, 60, lane);          FENCE(); }
    if (right) { patchR(sx, 60, W + 59, lane);  FENCE(); }   // last valid slot = 571

    // ---- barrier-free cascade; a/d stores issue per level and fly async ----
    wave_level<312, 28, 256, true >(sx,  sa1, h, a0row, d0row, c * 256, lane);
    FENCE();
    if (left)  { patchL(sa1, 28, lane);       FENCE(); }
    if (right) { patchR(sa1, 28, 283, lane);  FENCE(); }

    wave_level<152, 12, 128, true >(sa1, sa2, h, a1row, d1row, c * 128, lane);
    FENCE();
    if (left)  { patchL(sa2, 12, lane);       FENCE(); }
    if (right) { patchR(sa2, 12, 139, lane);  FENCE(); }

    wave_level< 72,  4,  64, true >(sa2, sa3, h, a2row, d2row, c * 64, lane);
    FENCE();
    if (left)  { patchL(sa3, 4, lane);        FENCE(); }
    if (right) { patchR(sa3, 4, 67, lane);    FENCE(); }

    wave_level< 32,  0,  32, false>(sa3, nullptr, h, a3row, d3row, c * 32, lane);
}

extern "C" void kernel_launch(void* const* d_in, const int* in_sizes, int n_in,
                              void* d_out, int out_size, void* d_ws, size_t ws_size,
                              hipStream_t stream) {
    (void)n_in; (void)d_ws; (void)ws_size; (void)out_size;

    const float* signal = (const float*)d_in[0];
    const float* h      = (const float*)d_in[1];
    float* out = (float*)d_out;

    const int L0 = 65536;
    const int R  = in_sizes[0] / L0;   // 512 rows
    const int LEVELS = 4;

    size_t s_off[4], d_off[4];
    {
        size_t off = 0;
        int L = L0;
        for (int l = 0; l < LEVELS; ++l) { s_off[l] = off; off += (size_t)R * (size_t)(L >> 1); L >>= 1; }
        L = L0;
        for (int l = 0; l < LEVELS; ++l) { d_off[l] = off; off += (size_t)R * (size_t)(L >> 1); L >>= 1; }
    }

    OutPtrs op;
    for (int l = 0; l < LEVELS; ++l) { op.a[l] = out + s_off[l]; op.d[l] = out + d_off[l]; }

    dim3 grid(L0 / W / (NT / 64), R);   // 32 x 512 = 16384 blocks, 4 indep waves each
    dim3 block(NT);
    dwt_wave_kernel<<<grid, block, 0, stream>>>(signal, h, op, L0);
}

// Round 6
// 75.315 us; speedup vs baseline: 1.0924x; 1.0557x over previous
//
#include <hip/hip_runtime.h>

#define KS 10
#define NT 256
#define W  512   // level-0 samples per WAVE (each wave fully independent)

// Per-wave LDS arena (floats): only a1..a3 live in LDS now.
//  sa1 [312] : a1 slots, pad 28 | own 256 | pad 28   (virtual v1 = o1-28+s)
//  sa2 [152] : a2 slots, pad 12 | own 128 | pad 12
//  sa3 [72]  : a3 slots, pad 4  | own 64  | pad 4
#define ARENA (312 + 152 + 72)   // 536 floats = 2144 B per wave

#define FENCE() asm volatile("s_waitcnt lgkmcnt(0)" ::: "memory")

struct OutPtrs { float* a[4]; float* d[4]; };

// levels 2..4: EXT extended outputs from LDS (float2 -> ds_read_b64), own a/d to global
template<int EXT, int PADO, int OWN, bool TO_LDS>
__device__ __forceinline__ void wave_level(const float* __restrict__ sIn,
                                           float* __restrict__ sOut,
                                           const float* h,
                                           float* __restrict__ aRow,
                                           float* __restrict__ dRow,
                                           int obase, int lane)
{
    constexpr int ITERS = (EXT + 63) / 64;
#pragma unroll
    for (int i = 0; i < ITERS; ++i) {
        const int t = lane + 64 * i;
        if ((EXT % 64 == 0) || (t < EXT)) {
            const float2* p2 = reinterpret_cast<const float2*>(sIn);
            float xin[10];
#pragma unroll
            for (int j = 0; j < 5; ++j) {           // [2t, 2t+10) as 5x ds_read_b64
                const float2 v = p2[t + j];
                xin[2 * j] = v.x; xin[2 * j + 1] = v.y;
            }
            float aa = 0.0f, dd = 0.0f;
#pragma unroll
            for (int k = 0; k < KS; ++k) {
                aa = fmaf(xin[k], h[k], aa);
                dd = fmaf(xin[k], (k & 1) ? -h[KS - 1 - k] : h[KS - 1 - k], dd);
            }
            if (TO_LDS) sOut[t] = aa;
            const int rel = t - PADO;
            if (rel >= 0 && rel < OWN) { aRow[obase + rel] = aa; dRow[obase + rel] = dd; }
        }
    }
}

__device__ __forceinline__ void patchL(float* s, int P, int lane) {
    if (lane < P) s[lane] = 2.0f * s[P] - s[2 * P - lane];
}
__device__ __forceinline__ void patchR(float* s, int P, int E, int lane) {
    if (lane < P) { const int t = E + 1 + lane; s[t] = 2.0f * s[E] - s[2 * E - t]; }
}

__global__ __launch_bounds__(NT) void dwt_wave_kernel(
    const float* __restrict__ x, const float* __restrict__ hptr, OutPtrs op, int L0)
{
    const int tid  = threadIdx.x;
    const int lane = tid & 63;
    const int wv   = tid >> 6;
    const int row  = blockIdx.y;
    const int nc   = L0 / W;                    // 128 chunks per row
    const int c    = blockIdx.x * (NT / 64) + wv;
    const bool left  = (c == 0);
    const bool right = (c == nc - 1);

    __shared__ __align__(16) float arena[(NT / 64) * ARENA];
    float* sa1 = arena + wv * ARENA;   // 312
    float* sa2 = sa1 + 312;            // 152
    float* sa3 = sa2 + 152;            // 72

    float h[KS];
#pragma unroll
    for (int k = 0; k < KS; ++k) h[k] = hptr[k];

    const int L1 = L0 >> 1, L2 = L0 >> 2, L3 = L0 >> 3, L4 = L0 >> 4;
    float* a0row = op.a[0] + (size_t)row * L1;  float* d0row = op.d[0] + (size_t)row * L1;
    float* a1row = op.a[1] + (size_t)row * L2;  float* d1row = op.d[1] + (size_t)row * L2;
    float* a2row = op.a[2] + (size_t)row * L3;  float* d2row = op.d[2] + (size_t)row * L3;
    float* a3row = op.a[3] + (size_t)row * L4;  float* d3row = op.d[3] + (size_t)row * L4;

    const float* xr = x + (size_t)row * (size_t)L0;
    const int o1 = c * 256;

    // ---- level 1: register-direct from global (no LDS on the x path) ----
    // thread owns a1/d1 at v1 in [o1+4*lane, o1+4*lane+4); needs x[X, X+16), X = 2*o1+8*lane-4
    {
        const int X = 2 * o1 + 8 * lane - 4;            // byte offset 16B-aligned
        float xv[16];
        const bool eT = (left && lane == 0) || (right && lane == 63);
        if (!eT) {
            const float4* p = reinterpret_cast<const float4*>(xr + X);
#pragma unroll
            for (int q = 0; q < 4; ++q) {
                const float4 v = p[q];
                xv[4 * q] = v.x; xv[4 * q + 1] = v.y; xv[4 * q + 2] = v.z; xv[4 * q + 3] = v.w;
            }
        } else {
#pragma unroll
            for (int t = 0; t < 16; ++t) {
                const int m = X + t;
                float v;
                if (m < 0)        v = 2.0f * xr[0]      - xr[-m];
                else if (m >= L0) v = 2.0f * xr[L0 - 1] - xr[2 * L0 - 2 - m];
                else              v = xr[m];
                xv[t] = v;
            }
        }
        float av[4], dv[4];
#pragma unroll
        for (int j = 0; j < 4; ++j) {
            float aa = 0.0f, dd = 0.0f;
#pragma unroll
            for (int k = 0; k < KS; ++k) {
                const float xx = xv[2 * j + k];
                aa = fmaf(xx, h[k], aa);
                dd = fmaf(xx, (k & 1) ? -h[KS - 1 - k] : h[KS - 1 - k], dd);
            }
            av[j] = aa; dv[j] = dd;
        }
        const int lane4 = 4 * lane;
        *reinterpret_cast<float4*>(a0row + o1 + lane4) = make_float4(av[0], av[1], av[2], av[3]);
        *reinterpret_cast<float4*>(d0row + o1 + lane4) = make_float4(dv[0], dv[1], dv[2], dv[3]);
        *reinterpret_cast<float4*>(sa1 + 28 + lane4)   = make_float4(av[0], av[1], av[2], av[3]);
    }

    // ---- a1 pad slots (28 each side) from global x, masked lanes ----
    {
        int ps = -1, v1p = 0;
        if (lane < 28)                     { ps = lane;              v1p = o1 - 28 + lane; }
        else if (lane >= 32 && lane < 60)  { ps = 284 + (lane - 32); v1p = o1 + 256 + (lane - 32); }
        const bool skip = (left && lane < 32) || (right && lane >= 32);
        if (ps >= 0 && !skip) {
            const int xb = 2 * v1p - 4;     // in-range for interior waves
            float acc = 0.0f;
#pragma unroll
            for (int k = 0; k < KS; ++k) acc = fmaf(xr[xb + k], h[k], acc);
            sa1[ps] = acc;
        }
    }
    FENCE();
    if (left)  { patchL(sa1, 28, lane);       FENCE(); }
    if (right) { patchR(sa1, 28, 283, lane);  FENCE(); }

    // ---- cascade levels 2..4 from LDS ----
    wave_level<152, 12, 128, true >(sa1, sa2, h, a1row, d1row, c * 128, lane);
    FENCE();
    if (left)  { patchL(sa2, 12, lane);       FENCE(); }
    if (right) { patchR(sa2, 12, 139, lane);  FENCE(); }

    wave_level< 72,  4,  64, true >(sa2, sa3, h, a2row, d2row, c * 64, lane);
    FENCE();
    if (left)  { patchL(sa3, 4, lane);        FENCE(); }
    if (right) { patchR(sa3, 4, 67, lane);    FENCE(); }

    wave_level< 32,  0,  32, false>(sa3, nullptr, h, a3row, d3row, c * 32, lane);
}

extern "C" void kernel_launch(void* const* d_in, const int* in_sizes, int n_in,
                              void* d_out, int out_size, void* d_ws, size_t ws_size,
                              hipStream_t stream) {
    (void)n_in; (void)d_ws; (void)ws_size; (void)out_size;

    const float* signal = (const float*)d_in[0];
    const float* h      = (const float*)d_in[1];
    float* out = (float*)d_out;

    const int L0 = 65536;
    const int R  = in_sizes[0] / L0;   // 512 rows
    const int LEVELS = 4;

    size_t s_off[4], d_off[4];
    {
        size_t off = 0;
        int L = L0;
        for (int l = 0; l < LEVELS; ++l) { s_off[l] = off; off += (size_t)R * (size_t)(L >> 1); L >>= 1; }
        L = L0;
        for (int l = 0; l < LEVELS; ++l) { d_off[l] = off; off += (size_t)R * (size_t)(L >> 1); L >>= 1; }
    }

    OutPtrs op;
    for (int l = 0; l < LEVELS; ++l) { op.a[l] = out + s_off[l]; op.d[l] = out + d_off[l]; }

    dim3 grid(L0 / W / (NT / 64), R);   // 32 x 512 blocks, 4 independent waves each
    dim3 block(NT);
    dwt_wave_kernel<<<grid, block, 0, stream>>>(signal, h, op, L0);
}

// Round 8
// 67.875 us; speedup vs baseline: 1.2122x; 1.1096x over previous
//
#include <hip/hip_runtime.h>

#define KS 10
#define NT 256
#define W  512   // level-0 samples per WAVE (each wave fully independent)

// Per-wave LDS arena (floats): only a1..a3 live in LDS.
//  sa1 [312] : a1 slots, pad 28 | own 256 | pad 28
//  sa2 [152] : a2 slots, pad 12 | own 128 | pad 12
//  sa3 [72]  : a3 slots, pad 4  | own 64  | pad 4
#define ARENA (312 + 152 + 72)   // 536 floats = 2144 B per wave

#define FENCE() asm volatile("s_waitcnt lgkmcnt(0)" ::: "memory")

typedef float f4 __attribute__((ext_vector_type(4)));   // native vector: ok for nontemporal builtin

struct OutPtrs { float* a[4]; float* d[4]; };

// levels 2..4: EXT extended outputs from LDS (float2 -> ds_read_b64), own a/d to global (nt)
template<int EXT, int PADO, int OWN, bool TO_LDS>
__device__ __forceinline__ void wave_level(const float* __restrict__ sIn,
                                           float* __restrict__ sOut,
                                           const float* h,
                                           float* __restrict__ aRow,
                                           float* __restrict__ dRow,
                                           int obase, int lane)
{
    constexpr int ITERS = (EXT + 63) / 64;
#pragma unroll
    for (int i = 0; i < ITERS; ++i) {
        const int t = lane + 64 * i;
        if ((EXT % 64 == 0) || (t < EXT)) {
            const float2* p2 = reinterpret_cast<const float2*>(sIn);
            float xin[10];
#pragma unroll
            for (int j = 0; j < 5; ++j) {           // [2t, 2t+10) as 5x ds_read_b64
                const float2 v = p2[t + j];
                xin[2 * j] = v.x; xin[2 * j + 1] = v.y;
            }
            float aa = 0.0f, dd = 0.0f;
#pragma unroll
            for (int k = 0; k < KS; ++k) {
                aa = fmaf(xin[k], h[k], aa);
                dd = fmaf(xin[k], (k & 1) ? -h[KS - 1 - k] : h[KS - 1 - k], dd);
            }
            if (TO_LDS) sOut[t] = aa;
            const int rel = t - PADO;
            if (rel >= 0 && rel < OWN) {
                __builtin_nontemporal_store(aa, aRow + obase + rel);
                __builtin_nontemporal_store(dd, dRow + obase + rel);
            }
        }
    }
}

__device__ __forceinline__ void patchL(float* s, int P, int lane) {
    if (lane < P) s[lane] = 2.0f * s[P] - s[2 * P - lane];
}
__device__ __forceinline__ void patchR(float* s, int P, int E, int lane) {
    if (lane < P) { const int t = E + 1 + lane; s[t] = 2.0f * s[E] - s[2 * E - t]; }
}

__global__ __launch_bounds__(NT) void dwt_wave_kernel(
    const float* __restrict__ x, const float* __restrict__ hptr, OutPtrs op, int L0)
{
    const int tid  = threadIdx.x;
    const int lane = tid & 63;
    const int wv   = tid >> 6;
    const int row  = blockIdx.y;
    const int nc   = L0 / W;                    // 128 chunks per row
    const int c    = blockIdx.x * (NT / 64) + wv;
    const bool left  = (c == 0);
    const bool right = (c == nc - 1);

    __shared__ __align__(16) float arena[(NT / 64) * ARENA];
    float* sa1 = arena + wv * ARENA;   // 312
    float* sa2 = sa1 + 312;            // 152
    float* sa3 = sa2 + 152;            // 72

    float h[KS];
#pragma unroll
    for (int k = 0; k < KS; ++k) h[k] = hptr[k];

    const int L1 = L0 >> 1, L2 = L0 >> 2, L3 = L0 >> 3, L4 = L0 >> 4;
    float* a0row = op.a[0] + (size_t)row * L1;  float* d0row = op.d[0] + (size_t)row * L1;
    float* a1row = op.a[1] + (size_t)row * L2;  float* d1row = op.d[1] + (size_t)row * L2;
    float* a2row = op.a[2] + (size_t)row * L3;  float* d2row = op.d[2] + (size_t)row * L3;
    float* a3row = op.a[3] + (size_t)row * L4;  float* d3row = op.d[3] + (size_t)row * L4;

    const float* xr = x + (size_t)row * (size_t)L0;
    const int o1 = c * 256;

    // ---- pad-slot x loads issued FIRST so their latency overlaps level-1 compute ----
    int ps = -1;
    float px[KS];
    {
        int v1p = 0;
        if (lane < 28)                     { ps = lane;              v1p = o1 - 28 + lane; }
        else if (lane >= 32 && lane < 60)  { ps = 284 + (lane - 32); v1p = o1 + 256 + (lane - 32); }
        const bool skip = (left && lane < 32) || (right && lane >= 32);
        if (skip) ps = -1;
        if (ps >= 0) {
            const int xb = 2 * v1p - 4;     // in-range for interior waves
#pragma unroll
            for (int k = 0; k < KS; ++k) px[k] = xr[xb + k];
        }
    }

    // ---- level 1: register-direct from global (no LDS on the x path) ----
    // thread owns a1/d1 at [o1+4*lane, o1+4*lane+4); needs x[X, X+16), X = 2*o1+8*lane-4
    {
        const int X = 2 * o1 + 8 * lane - 4;            // 16B-aligned
        float xv[16];
        const bool eT = (left && lane == 0) || (right && lane == 63);
        if (!eT) {
            const float4* p = reinterpret_cast<const float4*>(xr + X);
#pragma unroll
            for (int q = 0; q < 4; ++q) {
                const float4 v = p[q];
                xv[4 * q] = v.x; xv[4 * q + 1] = v.y; xv[4 * q + 2] = v.z; xv[4 * q + 3] = v.w;
            }
        } else {
#pragma unroll
            for (int t = 0; t < 16; ++t) {
                const int m = X + t;
                float v;
                if (m < 0)        v = 2.0f * xr[0]      - xr[-m];
                else if (m >= L0) v = 2.0f * xr[L0 - 1] - xr[2 * L0 - 2 - m];
                else              v = xr[m];
                xv[t] = v;
            }
        }
        float av[4], dv[4];
#pragma unroll
        for (int j = 0; j < 4; ++j) {
            float aa = 0.0f, dd = 0.0f;
#pragma unroll
            for (int k = 0; k < KS; ++k) {
                const float xx = xv[2 * j + k];
                aa = fmaf(xx, h[k], aa);
                dd = fmaf(xx, (k & 1) ? -h[KS - 1 - k] : h[KS - 1 - k], dd);
            }
            av[j] = aa; dv[j] = dd;
        }
        const int lane4 = 4 * lane;
        f4 avv = {av[0], av[1], av[2], av[3]};
        f4 dvv = {dv[0], dv[1], dv[2], dv[3]};
        __builtin_nontemporal_store(avv, reinterpret_cast<f4*>(a0row + o1 + lane4));
        __builtin_nontemporal_store(dvv, reinterpret_cast<f4*>(d0row + o1 + lane4));
        *reinterpret_cast<f4*>(sa1 + 28 + lane4) = avv;
    }

    // ---- finish a1 pad slots from the preloaded px ----
    if (ps >= 0) {
        float acc = 0.0f;
#pragma unroll
        for (int k = 0; k < KS; ++k) acc = fmaf(px[k], h[k], acc);
        sa1[ps] = acc;
    }
    FENCE();
    if (left)  { patchL(sa1, 28, lane);       FENCE(); }
    if (right) { patchR(sa1, 28, 283, lane);  FENCE(); }

    // ---- cascade levels 2..4 from LDS ----
    wave_level<152, 12, 128, true >(sa1, sa2, h, a1row, d1row, c * 128, lane);
    FENCE();
    if (left)  { patchL(sa2, 12, lane);       FENCE(); }
    if (right) { patchR(sa2, 12, 139, lane);  FENCE(); }

    wave_level< 72,  4,  64, true >(sa2, sa3, h, a2row, d2row, c * 64, lane);
    FENCE();
    if (left)  { patchL(sa3, 4, lane);        FENCE(); }
    if (right) { patchR(sa3, 4, 67, lane);    FENCE(); }

    wave_level< 32,  0,  32, false>(sa3, nullptr, h, a3row, d3row, c * 32, lane);
}

extern "C" void kernel_launch(void* const* d_in, const int* in_sizes, int n_in,
                              void* d_out, int out_size, void* d_ws, size_t ws_size,
                              hipStream_t stream) {
    (void)n_in; (void)d_ws; (void)ws_size; (void)out_size;

    const float* signal = (const float*)d_in[0];
    const float* h      = (const float*)d_in[1];
    float* out = (float*)d_out;

    const int L0 = 65536;
    const int R  = in_sizes[0] / L0;   // 512 rows
    const int LEVELS = 4;

    size_t s_off[4], d_off[4];
    {
        size_t off = 0;
        int L = L0;
        for (int l = 0; l < LEVELS; ++l) { s_off[l] = off; off += (size_t)R * (size_t)(L >> 1); L >>= 1; }
        L = L0;
        for (int l = 0; l < LEVELS; ++l) { d_off[l] = off; off += (size_t)R * (size_t)(L >> 1); L >>= 1; }
    }

    OutPtrs op;
    for (int l = 0; l < LEVELS; ++l) { op.a[l] = out + s_off[l]; op.d[l] = out + d_off[l]; }

    dim3 grid(L0 / W / (NT / 64), R);   // 32 x 512 blocks, 4 independent waves each
    dim3 block(NT);
    dwt_wave_kernel<<<grid, block, 0, stream>>>(signal, h, op, L0);
}